// Round 7
// baseline (3506.181 us; speedup 1.0000x reference)
//
#include <hip/hip_runtime.h>
#include <cstddef>

namespace {

constexpr int kH = 1024;
constexpr int kFF = 4096;
constexpr int kB = 8;
constexpr int kL = 12;
constexpr float kEps = 1e-5f;
constexpr int NBLK = 256;
constexpr int NTHR = 512;
constexpr int GBLK = 128;   // blocks per stack group

struct StackParams {
  const float *inw, *inb, *ow, *ob, *g1, *be1, *g2, *be2, *W1, *b1, *W2, *b2;
};

struct KArgs {
  unsigned* bar;
  float *emb, *y2, *xn, *part1, *part2, *pct, *pcl;
  const float *ct, *clinical, *W_ct, *b_ct, *W_cl, *b_cl, *norm_g, *norm_b;
  StackParams P0, P1;
  float* out;
};

// Issue 32 rows x 256 cols of W into pbuf via global_load_lds (no VGPR data
// path; loads stay outstanding until the next vmcnt-draining fence).
// Wcol must be pre-offset to the column base. Wave w loads rows 4w..4w+3.
__device__ __forceinline__ void prefetchRows(const float* __restrict__ Wcol,
                                             int N, float* pbuf, int t) {
  int w = t >> 6, lane = t & 63;
#pragma unroll
  for (int i = 0; i < 4; ++i) {
    int r = w * 4 + i;
    const float* gp = Wcol + (size_t)r * N + (lane << 2);
    float* lp = pbuf + r * 256;   // wave-uniform base; HW adds lane*16B
    __builtin_amdgcn_global_load_lds(
        (const __attribute__((address_space(1))) void*)gp,
        (__attribute__((address_space(3))) void*)lp, 16, 0, 0);
  }
}

// Sense-reversing barrier, R6 fence protocol (proven correct), plus:
//  - 8 flag replicas spread 4KB apart; each block polls replica (bid&7);
//    last arriver writes all 8 (kills single-line polling contention).
//  - optional weight prefetch issued AFTER the release fence so the HBM
//    stream overlaps the barrier wait; the acquire fence drains it.
__device__ __forceinline__ void barSync(unsigned* cnt, unsigned* flags,
                                        unsigned target, unsigned ep, int rep,
                                        const float* pf, int pfN, float* pbuf) {
  __syncthreads();
  __threadfence();      // release: drain stores + L2 writeback
  __syncthreads();
  if (pf) prefetchRows(pf, pfN, pbuf, threadIdx.x);
  if (threadIdx.x == 0) {
    unsigned old = __hip_atomic_fetch_add(cnt, 1u, __ATOMIC_ACQ_REL,
                                          __HIP_MEMORY_SCOPE_AGENT);
    if (old == target * ep - 1u) {
#pragma unroll
      for (int r = 0; r < 8; ++r)
        __hip_atomic_store(flags + r * 1024, ep, __ATOMIC_RELEASE,
                           __HIP_MEMORY_SCOPE_AGENT);
    } else {
      unsigned* myf = flags + rep * 1024;
      while (__hip_atomic_load(myf, __ATOMIC_RELAXED,
                               __HIP_MEMORY_SCOPE_AGENT) < ep)
        __builtin_amdgcn_s_sleep(8);
    }
  }
  __syncthreads();
  __threadfence();      // acquire: drains prefetch vmcnt + cache inv
}

// 8-wave block reduce of two values (sum).
__device__ __forceinline__ void blkRed2(float& a, float& c, float* red) {
#pragma unroll
  for (int m = 1; m < 64; m <<= 1) { a += __shfl_xor(a, m); c += __shfl_xor(c, m); }
  int w = threadIdx.x >> 6;
  __syncthreads();
  if ((threadIdx.x & 63) == 0) { red[w] = a; red[8 + w] = c; }
  __syncthreads();
  a = 0.f; c = 0.f;
#pragma unroll
  for (int j = 0; j < 8; ++j) { a += red[j]; c += red[8 + j]; }
}

__device__ __forceinline__ void blkRedMaxMin(float& a, float& c, float* red) {
#pragma unroll
  for (int m = 1; m < 64; m <<= 1) {
    a = fmaxf(a, __shfl_xor(a, m));
    c = fminf(c, __shfl_xor(c, m));
  }
  int w = threadIdx.x >> 6;
  __syncthreads();
  if ((threadIdx.x & 63) == 0) { red[w] = a; red[8 + w] = c; }
  __syncthreads();
  float ra = red[0], rc = red[8];
#pragma unroll
  for (int j = 1; j < 8; ++j) { ra = fmaxf(ra, red[j]); rc = fminf(rc, red[8 + j]); }
  a = ra; c = rc;
}

// Cross-wave reduce of acc[8][4] over 8 waves, store float4 per (b,col).
// s_red layout: [4][64][33] floats (pad 33 kills the stride-32 bank conflict).
__device__ __forceinline__ void reduce8store(float acc[kB][4], float* s_red,
                                             float* dst, int N, int c0, int t) {
  int w = t >> 6, lane = t & 63;
  float* slot = s_red + (size_t)((w & 3) * 64 + lane) * 33;
  if (w >= 4) {
#pragma unroll
    for (int f = 0; f < 32; ++f) slot[f] = acc[f >> 2][f & 3];
  }
  __syncthreads();
  if (w < 4) {
#pragma unroll
    for (int f = 0; f < 32; ++f) slot[f] += acc[f >> 2][f & 3];
  }
  __syncthreads();
  if (t < 256) {
    int lane2 = t & 63, p = t >> 6;
#pragma unroll
    for (int bb = 0; bb < 2; ++bb) {
      int b = p * 2 + bb, f0 = b * 4;
      float4 s = make_float4(0.f, 0.f, 0.f, 0.f);
#pragma unroll
      for (int ww = 0; ww < 4; ++ww) {
        const float* q = s_red + (size_t)(ww * 64 + lane2) * 33 + f0;
        s.x += q[0]; s.y += q[1]; s.z += q[2]; s.w += q[3];
      }
      *reinterpret_cast<float4*>(dst + (size_t)b * N + c0 + lane2 * 4) = s;
    }
  }
  __syncthreads();
}

// Embedding GEMV tile (all rows from global).
template <int RPW, int ROWS>
__device__ __forceinline__ void gemvTile(const float* __restrict__ Wrow, int N,
                                         const float* Xs, float* dstSlice,
                                         int c0, float* s_red, int t) {
  int w = t >> 6, lane = t & 63;
  float acc[kB][4];
#pragma unroll
  for (int b = 0; b < kB; ++b) { acc[b][0] = acc[b][1] = acc[b][2] = acc[b][3] = 0.f; }
  const float* Wp = Wrow + (size_t)(w * RPW) * N + c0 + (lane << 2);
#pragma unroll
  for (int i = 0; i < RPW; ++i) {
    float4 wv = *reinterpret_cast<const float4*>(Wp + (size_t)i * N);
    int r = w * RPW + i;
#pragma unroll
    for (int b = 0; b < kB; ++b) {
      float x = Xs[b * ROWS + r];
      acc[b][0] = fmaf(x, wv.x, acc[b][0]);
      acc[b][1] = fmaf(x, wv.y, acc[b][1]);
      acc[b][2] = fmaf(x, wv.z, acc[b][2]);
      acc[b][3] = fmaf(x, wv.w, acc[b][3]);
    }
  }
  reduce8store(acc, s_red, dstSlice, N, c0, t);
}

// 128-row x 256-col GEMV tile; rows 0-31 come from the LDS prefetch buffer,
// rows 32-127 stream from global. Wcol pre-offset to column base.
__device__ __forceinline__ void gemvTileP(const float* __restrict__ Wcol, int N,
                                          const float* Xs, const float* pbuf,
                                          float* dstSlice, int c0, float* s_red,
                                          int t) {
  int w = t >> 6, lane = t & 63;
  float acc[kB][4];
#pragma unroll
  for (int b = 0; b < kB; ++b) { acc[b][0] = acc[b][1] = acc[b][2] = acc[b][3] = 0.f; }
  if (w < 2) {  // rows 0..31 in pbuf
    const float* Lp = pbuf + (w * 16) * 256 + (lane << 2);
#pragma unroll
    for (int i = 0; i < 16; ++i) {
      float4 wv = *reinterpret_cast<const float4*>(Lp + i * 256);
      int r = w * 16 + i;
#pragma unroll
      for (int b = 0; b < kB; ++b) {
        float x = Xs[b * 128 + r];
        acc[b][0] = fmaf(x, wv.x, acc[b][0]);
        acc[b][1] = fmaf(x, wv.y, acc[b][1]);
        acc[b][2] = fmaf(x, wv.z, acc[b][2]);
        acc[b][3] = fmaf(x, wv.w, acc[b][3]);
      }
    }
  } else {
    const float* Wp = Wcol + (size_t)(w * 16) * N + (lane << 2);
#pragma unroll
    for (int i = 0; i < 16; ++i) {
      float4 wv = *reinterpret_cast<const float4*>(Wp + (size_t)i * N);
      int r = w * 16 + i;
#pragma unroll
      for (int b = 0; b < kB; ++b) {
        float x = Xs[b * 128 + r];
        acc[b][0] = fmaf(x, wv.x, acc[b][0]);
        acc[b][1] = fmaf(x, wv.y, acc[b][1]);
        acc[b][2] = fmaf(x, wv.z, acc[b][2]);
        acc[b][3] = fmaf(x, wv.w, acc[b][3]);
      }
    }
  }
  reduce8store(acc, s_red, dstSlice, N, c0, t);
}

__global__ __launch_bounds__(NTHR, 2) void fusedAll(KArgs a) {
  __shared__ float s_xs[1024];
  __shared__ float s_red[4 * 64 * 33];
  __shared__ float s_stats[32];
  __shared__ __align__(16) float pbuf[32 * 256];   // 32 KB prefetch buffer

  const int bid = blockIdx.x;
  const int t = threadIdx.x;
  const int s = bid >> 7;         // stack
  const int gid = bid & 127;      // index within stack group
  const int rep = bid & 7;        // flag replica to poll

  unsigned* gcnt = a.bar + 0;
  unsigned* scnt = a.bar + 32 + s * 32;
  unsigned* gflags = a.bar + 512;
  unsigned* sflags = a.bar + 512 + 128 + s * 128;

  const StackParams& P = s ? a.P1 : a.P0;
  // Per-phase block decodes (fixed per block across layers):
  const int b_ = gid >> 4, qt = gid & 15;                       // A
  const int kc1 = gid >> 4, fc1 = gid & 15;                     // G1
  const int k01 = kc1 * 128, c01 = fc1 * 256;
  const int kc2 = (gid >> 2) & 31, fc2 = gid & 3;               // G2
  const int k02 = kc2 * 128, c02 = fc2 * 256;
  (void)fc2;

  // ---- E1: embedding GEMV partials ----
  if (bid < 128) {  // ct @ W_ct : tiles 64 rows x 256 cols
    int kc = bid >> 2, fc = bid & 3;
    int k0 = kc * 64, c0 = fc * 256;
    { int b = t >> 6, r = t & 63; s_xs[b * 64 + r] = a.ct[b * 2048 + k0 + r]; }
    __syncthreads();
    gemvTile<8, 64>(a.W_ct + (size_t)k0 * kH, kH, s_xs,
                    a.pct + (size_t)kc * kB * kH, c0, s_red, t);
  } else if (bid < 160) {  // clinical @ W_cl : tiles 16 rows x 256 cols
    int bb = bid - 128;
    int kc = bb >> 2, fc = bb & 3;
    int k0 = kc * 16, c0 = fc * 256;
    if (t < 128) { int b = t >> 4, r = t & 15; s_xs[b * 16 + r] = a.clinical[b * 128 + k0 + r]; }
    __syncthreads();
    gemvTile<2, 16>(a.W_cl + (size_t)k0 * kH, kH, s_xs,
                    a.pcl + (size_t)kc * kB * kH, c0, s_red, t);
  }
  barSync(gcnt, gflags, NBLK, 1u, rep, nullptr, 0, pbuf);

  // ---- E2: reduce partials -> emb ----
  if (bid < 32) {
    int id = bid * NTHR + t;  // 0..16383
    int ss = id >> 13, n = id & 1023, bn = id & 8191;
    float sum;
    if (ss == 0) {
      sum = a.b_ct[n];
      const float* pp = a.pct + bn;
#pragma unroll 4
      for (int p = 0; p < 32; ++p) sum += pp[(size_t)p * 8192];
    } else {
      sum = a.b_cl[n];
      const float* pp = a.pcl + bn;
#pragma unroll
      for (int p = 0; p < 8; ++p) sum += pp[(size_t)p * 8192];
    }
    a.emb[id] = sum;
  }
  // prefetch W1(0) rows 0-31 across this barrier
  barSync(gcnt, gflags, NBLK, 2u, rep,
          P.W1 + (size_t)k01 * kFF + c01, kFF, pbuf);

  unsigned eps = 0;
  for (int l = 0; l < kL; ++l) {
    // ---- A: kv reconstruct + LN1 + rank-1 softmax attn + residual ----
    {
      const float* qr = a.emb + (size_t)((1 - s) * 8 + b_) * kH;
      float wi0 = P.inw[l * 3 + 0], wi1 = P.inw[l * 3 + 1], wi2 = P.inw[l * 3 + 2];
      float bi0 = P.inb[l * 3 + 0], bi1 = P.inb[l * 3 + 1], bi2 = P.inb[l * 3 + 2];
      float ow = P.ow[l], ob = P.ob[l];
      const float* g1 = P.g1 + (size_t)l * kH;
      const float* be1 = P.be1 + (size_t)l * kH;
      float2* kvp = reinterpret_cast<float2*>(s_red);

      float lsum = 0.f, lsq = 0.f;
#pragma unroll
      for (int i = 0; i < 2; ++i) {
        int n = t + i * NTHR;
        float x;
        if (l == 0) {
          x = a.emb[(size_t)(s * 8 + b_) * kH + n];
        } else {
          x = P.b2[(size_t)(l - 1) * kH + n] + a.xn[(size_t)(s * 8 + b_) * kH + n];
          const float* pp = a.part2 + ((size_t)(s * 32) * kB + b_) * kH + n;
#pragma unroll 8
          for (int p = 0; p < 32; ++p) x += pp[(size_t)p * kB * kH];
        }
        s_xs[n] = x;
        lsum += x;
        lsq += x * x;
      }
      blkRed2(lsum, lsq, s_stats);
      float mean = lsum * (1.f / kH);
      float rstd = rsqrtf(lsq * (1.f / kH) - mean * mean + kEps);

      float lmax = -1e30f, lmin = 1e30f;
#pragma unroll
      for (int i = 0; i < 2; ++i) {
        int n = t + i * NTHR;
        float x = s_xs[n];
        float kp = fmaf(x, wi1, bi1);
        float v = (x - mean) * rstd * g1[n] + be1[n];
        float vp = fmaf(v, wi2, bi2);
        kvp[n] = make_float2(kp, vp);
        lmax = fmaxf(lmax, kp);
        lmin = fminf(lmin, kp);
      }
      blkRedMaxMin(lmax, lmin, s_stats);  // syncs -> kvp visible

      int q = qt * 64 + (t >> 3), ks = t & 7;
      float sq_ = fmaf(qr[q], wi0, bi0);
      float mb = fmaxf(sq_ * lmax, sq_ * lmin);
      float den0 = 0.f, num0 = 0.f, den1 = 0.f, num1 = 0.f;
#pragma unroll 4
      for (int j = 0; j < 128; j += 2) {
        float2 av = kvp[ks + (j << 3)];
        float2 cv = kvp[ks + ((j + 1) << 3)];
        float e0 = __expf(fmaf(sq_, av.x, -mb));
        float e1 = __expf(fmaf(sq_, cv.x, -mb));
        den0 += e0; num0 = fmaf(e0, av.y, num0);
        den1 += e1; num1 = fmaf(e1, cv.y, num1);
      }
      float den = den0 + den1, num = num0 + num1;
#pragma unroll
      for (int m = 1; m < 8; m <<= 1) {
        den += __shfl_xor(den, m);
        num += __shfl_xor(num, m);
      }
      if (ks == 0) {
        float av = num / den;
        float vq = (s_xs[q] - mean) * rstd * g1[q] + be1[q];
        a.y2[(size_t)(s * 8 + b_) * kH + q] = fmaf(av, ow, ob) + vq;
      }
    }
    barSync(scnt, sflags, GBLK, ++eps, rep, nullptr, 0, pbuf);

    // ---- G1: LN2 + X@W1 partials (rows 0-31 from pbuf) ----
    {
      const float* y2s = a.y2 + (size_t)s * 8192;
      {
        int w = t >> 6, lane = t & 63;
        float sum = 0.f, sq = 0.f;
#pragma unroll
        for (int j = 0; j < 16; ++j) {
          float x = y2s[w * 1024 + lane + 64 * j];
          sum += x;
          sq += x * x;
        }
#pragma unroll
        for (int m = 1; m < 64; m <<= 1) { sum += __shfl_xor(sum, m); sq += __shfl_xor(sq, m); }
        if (lane == 0) {
          float mean = sum * (1.f / kH);
          s_stats[w] = mean;
          s_stats[8 + w] = rsqrtf(sq * (1.f / kH) - mean * mean + kEps);
        }
      }
      __syncthreads();
      const float* g2p = P.g2 + (size_t)l * kH + k01;
      const float* be2p = P.be2 + (size_t)l * kH + k01;
#pragma unroll
      for (int i = 0; i < 2; ++i) {
        int idx = t + i * NTHR;
        int b = idx >> 7, r = idx & 127;
        float x = y2s[b * 1024 + k01 + r];
        float v = (x - s_stats[b]) * s_stats[8 + b] * g2p[r] + be2p[r];
        s_xs[b * 128 + r] = v;
        if (fc1 == 0) a.xn[(size_t)(s * 8 + b) * kH + k01 + r] = v;
      }
      __syncthreads();
      gemvTileP(P.W1 + (size_t)l * kH * kFF + (size_t)k01 * kFF + c01, kFF,
                s_xs, pbuf, a.part1 + (size_t)(s * 8 + kc1) * kB * kFF, c01,
                s_red, t);
    }
    // prefetch W2(l) rows 0-31 across this barrier
    barSync(scnt, sflags, GBLK, ++eps, rep,
            P.W2 + (size_t)l * kFF * kH + (size_t)k02 * kH + c02, kH, pbuf);

    // ---- G2: gelu(h) @ W2 partials (rows 0-31 from pbuf) ----
    {
      const float* b1p = P.b1 + (size_t)l * kFF + k02;
#pragma unroll
      for (int i = 0; i < 2; ++i) {
        int idx = t + i * NTHR;
        int b = idx >> 7, r = idx & 127;
        const float* pp = a.part1 + ((size_t)(s * 8) * kB + b) * kFF + k02 + r;
        float h = b1p[r];
#pragma unroll
        for (int p = 0; p < 8; ++p) h += pp[(size_t)p * kB * kFF];
        s_xs[b * 128 + r] = 0.5f * h * (1.f + erff(h * 0.70710678118654752f));
      }
      __syncthreads();
      gemvTileP(P.W2 + (size_t)l * kFF * kH + (size_t)k02 * kH + c02, kH,
                s_xs, pbuf, a.part2 + (size_t)(s * 32 + kc2) * kB * kH, c02,
                s_red, t);
    }
    // prefetch W1(l+1) rows 0-31 across this barrier
    barSync(scnt, sflags, GBLK, ++eps, rep,
            (l + 1 < kL) ? (P.W1 + (size_t)(l + 1) * kH * kFF +
                            (size_t)k01 * kFF + c01)
                         : nullptr, kFF, pbuf);
  }

  barSync(gcnt, gflags, NBLK, 3u, rep, nullptr, 0, pbuf);

  // ---- F: final concat LayerNorm ----
  if (bid < 8) {
    int b = bid;
    float vals[4];
    float lsum = 0.f, lsq = 0.f;
#pragma unroll
    for (int i = 0; i < 4; ++i) {
      int idx = t + i * NTHR;  // 0..2047
      int ss = idx >> 10, n = idx & 1023;
      const StackParams& PP = ss ? a.P1 : a.P0;
      float x = PP.b2[(size_t)(kL - 1) * kH + n] + a.xn[(size_t)(ss * 8 + b) * kH + n];
      const float* pp = a.part2 + ((size_t)(ss * 32) * kB + b) * kH + n;
#pragma unroll 4
      for (int p = 0; p < 32; ++p) x += pp[(size_t)p * kB * kH];
      vals[i] = x;
      lsum += x;
      lsq += x * x;
    }
    blkRed2(lsum, lsq, s_stats);
    float mean = lsum * (1.f / 2048.f);
    float rstd = rsqrtf(lsq * (1.f / 2048.f) - mean * mean + kEps);
#pragma unroll
    for (int i = 0; i < 4; ++i) {
      int idx = t + i * NTHR;
      a.out[(size_t)b * 2048 + idx] = (vals[i] - mean) * rstd * a.norm_g[idx] + a.norm_b[idx];
    }
  }
}

}  // namespace

extern "C" void kernel_launch(void* const* d_in, const int* in_sizes, int n_in,
                              void* d_out, int out_size, void* d_ws, size_t ws_size,
                              hipStream_t stream) {
  KArgs ka;
  ka.ct = (const float*)d_in[0];
  ka.clinical = (const float*)d_in[1];
  ka.W_ct = (const float*)d_in[2];
  ka.b_ct = (const float*)d_in[3];
  ka.W_cl = (const float*)d_in[4];
  ka.b_cl = (const float*)d_in[5];
  ka.norm_g = (const float*)d_in[6];
  ka.norm_b = (const float*)d_in[7];

  ka.P0 = StackParams{(const float*)d_in[8],  (const float*)d_in[9],  (const float*)d_in[10],
                      (const float*)d_in[11], (const float*)d_in[12], (const float*)d_in[13],
                      (const float*)d_in[14], (const float*)d_in[15], (const float*)d_in[16],
                      (const float*)d_in[17], (const float*)d_in[18], (const float*)d_in[19]};
  ka.P1 = StackParams{(const float*)d_in[20], (const float*)d_in[21], (const float*)d_in[22],
                      (const float*)d_in[23], (const float*)d_in[24], (const float*)d_in[25],
                      (const float*)d_in[26], (const float*)d_in[27], (const float*)d_in[28],
                      (const float*)d_in[29], (const float*)d_in[30], (const float*)d_in[31]};

  ka.bar = (unsigned*)d_ws;                              // 32 KB barrier region
  float* base = (float*)((char*)d_ws + 32768);
  ka.emb = base;                                         // [2][8][1024]
  ka.y2 = ka.emb + 2 * kB * kH;                          // [2][8][1024]
  ka.xn = ka.y2 + 2 * kB * kH;                           // [2][8][1024]
  ka.part1 = ka.xn + 2 * kB * kH;                        // [2][8][8][4096]  = 2 MB
  ka.part2 = ka.part1 + (size_t)2 * 8 * kB * kFF;        // [2][32][8][1024] = 2 MB
  ka.pct = ka.part2 + (size_t)2 * 32 * kB * kH;          // [32][8][1024]    = 1 MB
  ka.pcl = ka.pct + (size_t)32 * kB * kH;                // [8][8][1024]
  ka.out = (float*)d_out;

  hipMemsetAsync(d_ws, 0, 32768, stream);
  void* params[] = {&ka};
  hipLaunchCooperativeKernel((void*)fusedAll, dim3(NBLK), dim3(NTHR), params, 0, stream);
}

// Round 8
// 731.151 us; speedup vs baseline: 4.7954x; 4.7954x over previous
//
#include <hip/hip_runtime.h>
#include <cstddef>

namespace {

constexpr int kH = 1024;
constexpr int kFF = 4096;
constexpr int kB = 8;
constexpr int kL = 12;
constexpr float kEps = 1e-5f;
constexpr int NBLK = 256;
constexpr int NTHR = 512;
constexpr int GBLK = 128;   // blocks per stack group

struct StackParams {
  const float *inw, *inb, *ow, *ob, *g1, *be1, *g2, *be2, *W1, *b1, *W2, *b2;
};

struct KArgs {
  unsigned* bar;
  float *emb, *y2, *xn, *part1, *part2, *pct, *pcl;
  const float *ct, *clinical, *W_ct, *b_ct, *W_cl, *b_cl, *norm_g, *norm_b;
  StackParams P0, P1;
  float* out;
};

// Sense-reversing barrier with ONE-THREAD fencing.
// Release: __syncthreads() drains all waves' vmcnt (compiler emits full
// s_waitcnt before s_barrier), leaving the block's stores in its XCD L2;
// thread0's RELEASE atomic then does the (single) L2 writeback.
// Acquire: thread0's ACQUIRE poll + one agent fence invalidates the CU's
// shared L1 + XCD L2 clean lines; trailing __syncthreads() orders all waves
// after it. 8 flag replicas 4KB apart kill single-line polling contention.
__device__ __forceinline__ void barSync(unsigned* cnt, unsigned* flags,
                                        unsigned target, unsigned ep, int rep) {
  __syncthreads();
  if (threadIdx.x == 0) {
    unsigned old = __hip_atomic_fetch_add(cnt, 1u, __ATOMIC_RELEASE,
                                          __HIP_MEMORY_SCOPE_AGENT);
    if (old == target * ep - 1u) {
#pragma unroll
      for (int r = 0; r < 8; ++r)
        __hip_atomic_store(flags + r * 1024, ep, __ATOMIC_RELEASE,
                           __HIP_MEMORY_SCOPE_AGENT);
    } else {
      unsigned* myf = flags + rep * 1024;
      while (__hip_atomic_load(myf, __ATOMIC_RELAXED,
                               __HIP_MEMORY_SCOPE_AGENT) < ep)
        __builtin_amdgcn_s_sleep(2);
    }
    __builtin_amdgcn_fence(__ATOMIC_ACQUIRE, "agent");  // L1+L2 inv, once
  }
  __syncthreads();
}

// 8-wave block reduce of two values (sum).
__device__ __forceinline__ void blkRed2(float& a, float& c, float* red) {
#pragma unroll
  for (int m = 1; m < 64; m <<= 1) { a += __shfl_xor(a, m); c += __shfl_xor(c, m); }
  int w = threadIdx.x >> 6;
  __syncthreads();
  if ((threadIdx.x & 63) == 0) { red[w] = a; red[8 + w] = c; }
  __syncthreads();
  a = 0.f; c = 0.f;
#pragma unroll
  for (int j = 0; j < 8; ++j) { a += red[j]; c += red[8 + j]; }
}

__device__ __forceinline__ void blkRedMaxMin(float& a, float& c, float* red) {
#pragma unroll
  for (int m = 1; m < 64; m <<= 1) {
    a = fmaxf(a, __shfl_xor(a, m));
    c = fminf(c, __shfl_xor(c, m));
  }
  int w = threadIdx.x >> 6;
  __syncthreads();
  if ((threadIdx.x & 63) == 0) { red[w] = a; red[8 + w] = c; }
  __syncthreads();
  float ra = red[0], rc = red[8];
#pragma unroll
  for (int j = 1; j < 8; ++j) { ra = fmaxf(ra, red[j]); rc = fminf(rc, red[8 + j]); }
  a = ra; c = rc;
}

// Cross-wave reduce of acc[8][4] over 8 waves, store float4 per (b,col).
// s_red layout: [4][64][33] floats (pad 33 kills the stride-32 bank conflict).
__device__ __forceinline__ void reduce8store(float acc[kB][4], float* s_red,
                                             float* dst, int N, int c0, int t) {
  int w = t >> 6, lane = t & 63;
  float* slot = s_red + (size_t)((w & 3) * 64 + lane) * 33;
  if (w >= 4) {
#pragma unroll
    for (int f = 0; f < 32; ++f) slot[f] = acc[f >> 2][f & 3];
  }
  __syncthreads();
  if (w < 4) {
#pragma unroll
    for (int f = 0; f < 32; ++f) slot[f] += acc[f >> 2][f & 3];
  }
  __syncthreads();
  if (t < 256) {
    int lane2 = t & 63, p = t >> 6;
#pragma unroll
    for (int bb = 0; bb < 2; ++bb) {
      int b = p * 2 + bb, f0 = b * 4;
      float4 s = make_float4(0.f, 0.f, 0.f, 0.f);
#pragma unroll
      for (int ww = 0; ww < 4; ++ww) {
        const float* q = s_red + (size_t)(ww * 64 + lane2) * 33 + f0;
        s.x += q[0]; s.y += q[1]; s.z += q[2]; s.w += q[3];
      }
      *reinterpret_cast<float4*>(dst + (size_t)b * N + c0 + lane2 * 4) = s;
    }
  }
  __syncthreads();
}

// Batched GEMV tile: ROWS rows x 256 cols, wave-contiguous 1KB row-segment
// loads (direct from global; no reg prefetch -> no spill; 128 VGPR).
template <int RPW, int ROWS>
__device__ __forceinline__ void gemvTile(const float* __restrict__ Wrow, int N,
                                         const float* Xs, float* dstSlice,
                                         int c0, float* s_red, int t) {
  int w = t >> 6, lane = t & 63;
  float acc[kB][4];
#pragma unroll
  for (int b = 0; b < kB; ++b) { acc[b][0] = acc[b][1] = acc[b][2] = acc[b][3] = 0.f; }
  const float* Wp = Wrow + (size_t)(w * RPW) * N + c0 + (lane << 2);
#pragma unroll
  for (int i = 0; i < RPW; ++i) {
    float4 wv = *reinterpret_cast<const float4*>(Wp + (size_t)i * N);
    int r = w * RPW + i;
#pragma unroll
    for (int b = 0; b < kB; ++b) {
      float x = Xs[b * ROWS + r];
      acc[b][0] = fmaf(x, wv.x, acc[b][0]);
      acc[b][1] = fmaf(x, wv.y, acc[b][1]);
      acc[b][2] = fmaf(x, wv.z, acc[b][2]);
      acc[b][3] = fmaf(x, wv.w, acc[b][3]);
    }
  }
  reduce8store(acc, s_red, dstSlice, N, c0, t);
}

__global__ __launch_bounds__(NTHR, 2) void fusedAll(KArgs a) {
  __shared__ float s_xs[1024];
  __shared__ float s_red[4 * 64 * 33];
  __shared__ float s_stats[32];

  const int bid = blockIdx.x;
  const int t = threadIdx.x;
  const int s = bid >> 7;         // stack
  const int gid = bid & 127;      // index within stack group
  const int rep = bid & 7;        // flag replica to poll

  unsigned* gcnt = a.bar + 0;
  unsigned* scnt = a.bar + 32 + s * 32;
  unsigned* gflags = a.bar + 512;
  unsigned* sflags = a.bar + 512 + 128 + s * 128;

  // ---- E1: embedding GEMV partials ----
  if (bid < 128) {  // ct @ W_ct : tiles 64 rows x 256 cols
    int kc = bid >> 2, fc = bid & 3;
    int k0 = kc * 64, c0 = fc * 256;
    { int b = t >> 6, r = t & 63; s_xs[b * 64 + r] = a.ct[b * 2048 + k0 + r]; }
    __syncthreads();
    gemvTile<8, 64>(a.W_ct + (size_t)k0 * kH, kH, s_xs,
                    a.pct + (size_t)kc * kB * kH, c0, s_red, t);
  } else if (bid < 160) {  // clinical @ W_cl : tiles 16 rows x 256 cols
    int bb = bid - 128;
    int kc = bb >> 2, fc = bb & 3;
    int k0 = kc * 16, c0 = fc * 256;
    if (t < 128) { int b = t >> 4, r = t & 15; s_xs[b * 16 + r] = a.clinical[b * 128 + k0 + r]; }
    __syncthreads();
    gemvTile<2, 16>(a.W_cl + (size_t)k0 * kH, kH, s_xs,
                    a.pcl + (size_t)kc * kB * kH, c0, s_red, t);
  }
  barSync(gcnt, gflags, NBLK, 1u, rep);

  // ---- E2: reduce partials -> emb ----
  if (bid < 32) {
    int id = bid * NTHR + t;  // 0..16383
    int ss = id >> 13, n = id & 1023, bn = id & 8191;
    float sum;
    if (ss == 0) {
      sum = a.b_ct[n];
      const float* pp = a.pct + bn;
#pragma unroll 4
      for (int p = 0; p < 32; ++p) sum += pp[(size_t)p * 8192];
    } else {
      sum = a.b_cl[n];
      const float* pp = a.pcl + bn;
#pragma unroll
      for (int p = 0; p < 8; ++p) sum += pp[(size_t)p * 8192];
    }
    a.emb[id] = sum;
  }
  barSync(gcnt, gflags, NBLK, 2u, rep);

  const StackParams& P = s ? a.P1 : a.P0;
  // Per-phase block decodes (fixed per block across layers):
  const int b_ = gid >> 4, qt = gid & 15;                       // A
  const int kc1 = gid >> 4, fc1 = gid & 15;                     // G1
  const int k01 = kc1 * 128, c01 = fc1 * 256;
  const int kc2 = (gid >> 2) & 31, fc2 = gid & 3;               // G2
  const int k02 = kc2 * 128, c02 = fc2 * 256;
  (void)fc2;

  unsigned eps = 0;
  for (int l = 0; l < kL; ++l) {
    // ---- A: kv reconstruct + LN1 + rank-1 softmax attn + residual ----
    {
      const float* qr = a.emb + (size_t)((1 - s) * 8 + b_) * kH;
      float wi0 = P.inw[l * 3 + 0], wi1 = P.inw[l * 3 + 1], wi2 = P.inw[l * 3 + 2];
      float bi0 = P.inb[l * 3 + 0], bi1 = P.inb[l * 3 + 1], bi2 = P.inb[l * 3 + 2];
      float ow = P.ow[l], ob = P.ob[l];
      const float* g1 = P.g1 + (size_t)l * kH;
      const float* be1 = P.be1 + (size_t)l * kH;
      float2* kvp = reinterpret_cast<float2*>(s_red);

      float lsum = 0.f, lsq = 0.f;
#pragma unroll
      for (int i = 0; i < 2; ++i) {
        int n = t + i * NTHR;
        float x;
        if (l == 0) {
          x = a.emb[(size_t)(s * 8 + b_) * kH + n];
        } else {
          x = P.b2[(size_t)(l - 1) * kH + n] + a.xn[(size_t)(s * 8 + b_) * kH + n];
          const float* pp = a.part2 + ((size_t)(s * 32) * kB + b_) * kH + n;
#pragma unroll 8
          for (int p = 0; p < 32; ++p) x += pp[(size_t)p * kB * kH];
        }
        s_xs[n] = x;
        lsum += x;
        lsq += x * x;
      }
      blkRed2(lsum, lsq, s_stats);
      float mean = lsum * (1.f / kH);
      float rstd = rsqrtf(lsq * (1.f / kH) - mean * mean + kEps);

      float lmax = -1e30f, lmin = 1e30f;
#pragma unroll
      for (int i = 0; i < 2; ++i) {
        int n = t + i * NTHR;
        float x = s_xs[n];
        float kp = fmaf(x, wi1, bi1);
        float v = (x - mean) * rstd * g1[n] + be1[n];
        float vp = fmaf(v, wi2, bi2);
        kvp[n] = make_float2(kp, vp);
        lmax = fmaxf(lmax, kp);
        lmin = fminf(lmin, kp);
      }
      blkRedMaxMin(lmax, lmin, s_stats);  // syncs -> kvp visible

      int q = qt * 64 + (t >> 3), ks = t & 7;
      float sq_ = fmaf(qr[q], wi0, bi0);
      float mb = fmaxf(sq_ * lmax, sq_ * lmin);
      float den0 = 0.f, num0 = 0.f, den1 = 0.f, num1 = 0.f;
#pragma unroll 4
      for (int j = 0; j < 128; j += 2) {
        float2 av = kvp[ks + (j << 3)];
        float2 cv = kvp[ks + ((j + 1) << 3)];
        float e0 = __expf(fmaf(sq_, av.x, -mb));
        float e1 = __expf(fmaf(sq_, cv.x, -mb));
        den0 += e0; num0 = fmaf(e0, av.y, num0);
        den1 += e1; num1 = fmaf(e1, cv.y, num1);
      }
      float den = den0 + den1, num = num0 + num1;
#pragma unroll
      for (int m = 1; m < 8; m <<= 1) {
        den += __shfl_xor(den, m);
        num += __shfl_xor(num, m);
      }
      if (ks == 0) {
        float av = num / den;
        float vq = (s_xs[q] - mean) * rstd * g1[q] + be1[q];
        a.y2[(size_t)(s * 8 + b_) * kH + q] = fmaf(av, ow, ob) + vq;
      }
    }
    barSync(scnt, sflags, GBLK, ++eps, rep);

    // ---- G1: LN2 + X@W1 partials (tiles 128 rows x 256 cols) ----
    {
      const float* y2s = a.y2 + (size_t)s * 8192;
      {
        int w = t >> 6, lane = t & 63;
        float sum = 0.f, sq = 0.f;
#pragma unroll
        for (int j = 0; j < 16; ++j) {
          float x = y2s[w * 1024 + lane + 64 * j];
          sum += x;
          sq += x * x;
        }
#pragma unroll
        for (int m = 1; m < 64; m <<= 1) { sum += __shfl_xor(sum, m); sq += __shfl_xor(sq, m); }
        if (lane == 0) {
          float mean = sum * (1.f / kH);
          s_stats[w] = mean;
          s_stats[8 + w] = rsqrtf(sq * (1.f / kH) - mean * mean + kEps);
        }
      }
      __syncthreads();
      const float* g2p = P.g2 + (size_t)l * kH + k01;
      const float* be2p = P.be2 + (size_t)l * kH + k01;
#pragma unroll
      for (int i = 0; i < 2; ++i) {
        int idx = t + i * NTHR;
        int b = idx >> 7, r = idx & 127;
        float x = y2s[b * 1024 + k01 + r];
        float v = (x - s_stats[b]) * s_stats[8 + b] * g2p[r] + be2p[r];
        s_xs[b * 128 + r] = v;
        if (fc1 == 0) a.xn[(size_t)(s * 8 + b) * kH + k01 + r] = v;
      }
      __syncthreads();
      gemvTile<16, 128>(P.W1 + (size_t)l * kH * kFF + (size_t)k01 * kFF, kFF,
                        s_xs, a.part1 + (size_t)(s * 8 + kc1) * kB * kFF, c01, s_red, t);
    }
    barSync(scnt, sflags, GBLK, ++eps, rep);

    // ---- G2: gelu(h) @ W2 partials (tiles 128 rows x 256 cols) ----
    {
      const float* b1p = P.b1 + (size_t)l * kFF + k02;
#pragma unroll
      for (int i = 0; i < 2; ++i) {
        int idx = t + i * NTHR;
        int b = idx >> 7, r = idx & 127;
        const float* pp = a.part1 + ((size_t)(s * 8) * kB + b) * kFF + k02 + r;
        float h = b1p[r];
#pragma unroll
        for (int p = 0; p < 8; ++p) h += pp[(size_t)p * kB * kFF];
        s_xs[b * 128 + r] = 0.5f * h * (1.f + erff(h * 0.70710678118654752f));
      }
      __syncthreads();
      gemvTile<16, 128>(P.W2 + (size_t)l * kFF * kH + (size_t)k02 * kH, kH,
                        s_xs, a.part2 + (size_t)(s * 32 + kc2) * kB * kH, c02, s_red, t);
    }
    barSync(scnt, sflags, GBLK, ++eps, rep);
  }

  barSync(gcnt, gflags, NBLK, 3u, rep);

  // ---- F: final concat LayerNorm ----
  if (bid < 8) {
    int b = bid;
    float vals[4];
    float lsum = 0.f, lsq = 0.f;
#pragma unroll
    for (int i = 0; i < 4; ++i) {
      int idx = t + i * NTHR;  // 0..2047
      int ss = idx >> 10, n = idx & 1023;
      const StackParams& PP = ss ? a.P1 : a.P0;
      float x = PP.b2[(size_t)(kL - 1) * kH + n] + a.xn[(size_t)(ss * 8 + b) * kH + n];
      const float* pp = a.part2 + ((size_t)(ss * 32) * kB + b) * kH + n;
#pragma unroll 4
      for (int p = 0; p < 32; ++p) x += pp[(size_t)p * kB * kH];
      vals[i] = x;
      lsum += x;
      lsq += x * x;
    }
    blkRed2(lsum, lsq, s_stats);
    float mean = lsum * (1.f / 2048.f);
    float rstd = rsqrtf(lsq * (1.f / 2048.f) - mean * mean + kEps);
#pragma unroll
    for (int i = 0; i < 4; ++i) {
      int idx = t + i * NTHR;
      a.out[(size_t)b * 2048 + idx] = (vals[i] - mean) * rstd * a.norm_g[idx] + a.norm_b[idx];
    }
  }
}

}  // namespace

extern "C" void kernel_launch(void* const* d_in, const int* in_sizes, int n_in,
                              void* d_out, int out_size, void* d_ws, size_t ws_size,
                              hipStream_t stream) {
  KArgs ka;
  ka.ct = (const float*)d_in[0];
  ka.clinical = (const float*)d_in[1];
  ka.W_ct = (const float*)d_in[2];
  ka.b_ct = (const float*)d_in[3];
  ka.W_cl = (const float*)d_in[4];
  ka.b_cl = (const float*)d_in[5];
  ka.norm_g = (const float*)d_in[6];
  ka.norm_b = (const float*)d_in[7];

  ka.P0 = StackParams{(const float*)d_in[8],  (const float*)d_in[9],  (const float*)d_in[10],
                      (const float*)d_in[11], (const float*)d_in[12], (const float*)d_in[13],
                      (const float*)d_in[14], (const float*)d_in[15], (const float*)d_in[16],
                      (const float*)d_in[17], (const float*)d_in[18], (const float*)d_in[19]};
  ka.P1 = StackParams{(const float*)d_in[20], (const float*)d_in[21], (const float*)d_in[22],
                      (const float*)d_in[23], (const float*)d_in[24], (const float*)d_in[25],
                      (const float*)d_in[26], (const float*)d_in[27], (const float*)d_in[28],
                      (const float*)d_in[29], (const float*)d_in[30], (const float*)d_in[31]};

  ka.bar = (unsigned*)d_ws;                              // 32 KB barrier region
  float* base = (float*)((char*)d_ws + 32768);
  ka.emb = base;                                         // [2][8][1024]
  ka.y2 = ka.emb + 2 * kB * kH;                          // [2][8][1024]
  ka.xn = ka.y2 + 2 * kB * kH;                           // [2][8][1024]
  ka.part1 = ka.xn + 2 * kB * kH;                        // [2][8][8][4096]  = 2 MB
  ka.part2 = ka.part1 + (size_t)2 * 8 * kB * kFF;        // [2][32][8][1024] = 2 MB
  ka.pct = ka.part2 + (size_t)2 * 32 * kB * kH;          // [32][8][1024]    = 1 MB
  ka.pcl = ka.pct + (size_t)32 * kB * kH;                // [8][8][1024]
  ka.out = (float*)d_out;

  hipMemsetAsync(d_ws, 0, 32768, stream);
  void* params[] = {&ka};
  hipLaunchCooperativeKernel((void*)fusedAll, dim3(NBLK), dim3(NTHR), params, 0, stream);
}